// Round 4
// baseline (6677.390 us; speedup 1.0000x reference)
//
#include <hip/hip_runtime.h>
#include <cstddef>

#define NN 50000
#define EE 800000

__device__ __forceinline__ void atomAdd(float* p, float v) {
  __hip_atomic_fetch_add(p, v, __ATOMIC_RELAXED, __HIP_MEMORY_SCOPE_AGENT);
}

// ---------------- degree / norm precompute ----------------
__global__ void k_deg_init(float* __restrict__ deg) {
  int i = blockIdx.x * 256 + threadIdx.x;
  if (i < NN) deg[i] = 1.0f;  // self-loop weight
}

__global__ void k_deg_acc(const int* __restrict__ dst, const float* __restrict__ ew,
                          float* __restrict__ deg) {
  int e = blockIdx.x * 256 + threadIdx.x;
  if (e < EE) {
    int d = dst[e];
    if (d >= 0 && d < NN) atomAdd(&deg[d], ew[e]);
  }
}

__global__ void k_dis(float* __restrict__ deg) {
  int i = blockIdx.x * 256 + threadIdx.x;
  if (i < NN) deg[i] = rsqrtf(deg[i]);  // in-place: deg -> dis
}

__global__ void k_edgenorm(const int* __restrict__ src, const int* __restrict__ dst,
                           const float* __restrict__ ew, const float* __restrict__ dis,
                           float* __restrict__ nrm) {
  int e = blockIdx.x * 256 + threadIdx.x;
  if (e < EE) {
    int s = src[e], d = dst[e];
    float v = 0.f;
    if (s >= 0 && s < NN && d >= 0 && d < NN) v = dis[s] * ew[e] * dis[d];
    nrm[e] = v;
  }
}

// BN folded to per-feature affine: bn(h) = h*s + (beta - mean*s)
__global__ void k_affine(const float* __restrict__ g1, const float* __restrict__ be1,
                         const float* __restrict__ m1, const float* __restrict__ v1,
                         const float* __restrict__ g2, const float* __restrict__ be2,
                         const float* __restrict__ m2, const float* __restrict__ v2,
                         float* __restrict__ s1, float* __restrict__ u1,
                         float* __restrict__ s2, float* __restrict__ u2) {
  int f = threadIdx.x;  // 256 threads
  float a1 = g1[f] * rsqrtf(v1[f] + 1e-5f);
  s1[f] = a1; u1[f] = be1[f] - m1[f] * a1;
  float a2 = g2[f] * rsqrtf(v2[f] + 1e-5f);
  s2[f] = a2; u2[f] = be2[f] - m2[f] * a2;
}

// ---------------- fp32 tiled GEMM: C[M,NOUT] = act(A)[M,K] @ B[K,NOUT] ----------------
// 64x64 tile, BK=16, 256 threads, 4x4 micro-tile. K/NOUT runtime; fuse = BN+ReLU on A.
__global__ __launch_bounds__(256) void k_gemm(const float* __restrict__ A,
                                              const float* __restrict__ B,
                                              float* __restrict__ C,
                                              const float* __restrict__ s,
                                              const float* __restrict__ u,
                                              int M, int K, int NOUT, int fuse) {
  __shared__ float As[16][68];  // [k][m], stride 272B = 17*16 keeps float4 alignment
  __shared__ float Bs[16][68];  // [k][n]
  const int tid = threadIdx.x;
  const int bm = blockIdx.y << 6;
  const int bn = blockIdx.x << 6;
  const int tx = tid & 15, ty = tid >> 4;
  const int arow = tid >> 2, acol = (tid & 3) << 2;   // A: 64 rows x 16 k
  const int brow = tid >> 4, bcol = (tid & 15) << 2;  // B: 16 k x 64 cols
  float acc[4][4] = {};
  const int gr = bm + arow;
  const float* Aptr = A + (size_t)gr * K;

  for (int k0 = 0; k0 < K; k0 += 16) {
    float4 av = make_float4(0.f, 0.f, 0.f, 0.f);
    if (gr < M) {
      av = *(const float4*)(Aptr + k0 + acol);
      if (fuse) {
        int kk = k0 + acol;
        av.x = fmaxf(fmaf(av.x, s[kk + 0], u[kk + 0]), 0.f);
        av.y = fmaxf(fmaf(av.y, s[kk + 1], u[kk + 1]), 0.f);
        av.z = fmaxf(fmaf(av.z, s[kk + 2], u[kk + 2]), 0.f);
        av.w = fmaxf(fmaf(av.w, s[kk + 3], u[kk + 3]), 0.f);
      }
    }
    float4 bv = *(const float4*)(B + (size_t)(k0 + brow) * NOUT + bn + bcol);
    As[acol + 0][arow] = av.x;
    As[acol + 1][arow] = av.y;
    As[acol + 2][arow] = av.z;
    As[acol + 3][arow] = av.w;
    *(float4*)&Bs[brow][bcol] = bv;
    __syncthreads();
#pragma unroll
    for (int k = 0; k < 16; ++k) {
      float4 rav = *(const float4*)&As[k][ty << 2];
      float4 rbv = *(const float4*)&Bs[k][tx << 2];
      float ar[4] = {rav.x, rav.y, rav.z, rav.w};
      float br[4] = {rbv.x, rbv.y, rbv.z, rbv.w};
#pragma unroll
      for (int r = 0; r < 4; ++r)
#pragma unroll
        for (int c = 0; c < 4; ++c) acc[r][c] = fmaf(ar[r], br[c], acc[r][c]);
    }
    __syncthreads();
  }
#pragma unroll
  for (int r = 0; r < 4; ++r) {
    int grow = bm + (ty << 2) + r;
    if (grow < M) {
      float4 v = make_float4(acc[r][0], acc[r][1], acc[r][2], acc[r][3]);
      *(float4*)(C + (size_t)grow * NOUT + bn + (tx << 2)) = v;
    }
  }
}

// ---------------- self-loop init: out[i,f] = dis[i]^2 * hW[i,f] + b[f] ----------------
__global__ void k_self256(const float* __restrict__ hW, const float* __restrict__ dis,
                          const float* __restrict__ b, float* __restrict__ out) {
  int j = blockIdx.x * 256 + threadIdx.x;   // NN*64 float4-groups
  if (j >= NN * 64) return;
  int i = j >> 6, q = j & 63;
  float d = dis[i];
  float d2 = d * d;
  float4 a = *(const float4*)(hW + (size_t)i * 256 + (q << 2));
  float4 bb = *(const float4*)(b + (q << 2));
  float4 o;
  o.x = fmaf(a.x, d2, bb.x);
  o.y = fmaf(a.y, d2, bb.y);
  o.z = fmaf(a.z, d2, bb.z);
  o.w = fmaf(a.w, d2, bb.w);
  *(float4*)(out + (size_t)i * 256 + (q << 2)) = o;
}

__global__ void k_self128(const float* __restrict__ hW, const float* __restrict__ dis,
                          const float* __restrict__ b, float* __restrict__ out) {
  int j = blockIdx.x * 256 + threadIdx.x;   // NN*32 float4-groups
  if (j >= NN * 32) return;
  int i = j >> 5, q = j & 31;
  float d = dis[i];
  float d2 = d * d;
  float4 a = *(const float4*)(hW + (size_t)i * 128 + (q << 2));
  float4 bb = *(const float4*)(b + (q << 2));
  float4 o;
  o.x = fmaf(a.x, d2, bb.x);
  o.y = fmaf(a.y, d2, bb.y);
  o.z = fmaf(a.z, d2, bb.z);
  o.w = fmaf(a.w, d2, bb.w);
  *(float4*)(out + (size_t)i * 128 + (q << 2)) = o;
}

// ---------------- edge scatter: out[dst] += norm_e * hW[src], one wave per edge --------
__global__ __launch_bounds__(256) void k_scatter256(const float* __restrict__ hW,
                                                    const float* __restrict__ nrm,
                                                    const int* __restrict__ src,
                                                    const int* __restrict__ dst,
                                                    float* __restrict__ out) {
  int e = (blockIdx.x << 2) + (threadIdx.x >> 6);
  if (e >= EE) return;
  int lane = threadIdx.x & 63;
  int si = src[e], di = dst[e];
  if (si < 0 || si >= NN || di < 0 || di >= NN) return;
  float w = nrm[e];
  float4 a = *(const float4*)(hW + (size_t)si * 256 + (lane << 2));
  float* o = out + (size_t)di * 256 + (lane << 2);
  atomAdd(o + 0, a.x * w);
  atomAdd(o + 1, a.y * w);
  atomAdd(o + 2, a.z * w);
  atomAdd(o + 3, a.w * w);
}

__global__ __launch_bounds__(256) void k_scatter128(const float* __restrict__ hW,
                                                    const float* __restrict__ nrm,
                                                    const int* __restrict__ src,
                                                    const int* __restrict__ dst,
                                                    float* __restrict__ out) {
  int e = (blockIdx.x << 2) + (threadIdx.x >> 6);
  if (e >= EE) return;
  int lane = threadIdx.x & 63;
  int si = src[e], di = dst[e];
  if (si < 0 || si >= NN || di < 0 || di >= NN) return;
  float w = nrm[e];
  float2 a = *(const float2*)(hW + (size_t)si * 128 + (lane << 1));
  float* o = out + (size_t)di * 128 + (lane << 1);
  atomAdd(o + 0, a.x * w);
  atomAdd(o + 1, a.y * w);
}

// ---------------- row L2 normalize: read ws, WRITE-ONLY plain stores to d_out --------
__global__ __launch_bounds__(256) void k_l2(const float* __restrict__ in,
                                            float* __restrict__ out) {
  int r = (blockIdx.x << 2) + (threadIdx.x >> 6);
  if (r >= NN) return;
  int lane = threadIdx.x & 63;
  float2 v = *(const float2*)(in + (size_t)r * 128 + (lane << 1));
  float ss = fmaf(v.x, v.x, v.y * v.y);
#pragma unroll
  for (int o = 32; o > 0; o >>= 1) ss += __shfl_xor(ss, o, 64);
  float sc = 1.0f / fmaxf(sqrtf(ss), 1e-12f);
  v.x *= sc;
  v.y *= sc;
  *(float2*)(out + (size_t)r * 128 + (lane << 1)) = v;
}

extern "C" void kernel_launch(void* const* d_in, const int* in_sizes, int n_in,
                              void* d_out, int out_size, void* d_ws, size_t ws_size,
                              hipStream_t stream) {
  // Workspace layout (float offsets):
  //   dis [0,50048)  nrm [50048,850048)  s1/u1/s2/u2 [850048,851072)
  //   hW  [851072, +N*256)   h [+N*256)   ob [+N*128)
  const size_t OFF_NRM = 50048;
  const size_t OFF_AFF = 850048;
  const size_t OFF_HW  = 851072;
  const size_t OFF_H   = OFF_HW + (size_t)NN * 256;
  const size_t OFF_OB  = OFF_H + (size_t)NN * 256;
  const size_t WS_FLOATS = OFF_OB + (size_t)NN * 128 + 256;
  if (ws_size < WS_FLOATS * sizeof(float)) return;  // fail cleanly, never OOB

  const float* x  = (const float*)d_in[0];
  const int* ei   = (const int*)d_in[1];
  const float* ew = (const float*)d_in[2];
  const float* W1 = (const float*)d_in[3];
  const float* b1 = (const float*)d_in[4];
  const float* W2 = (const float*)d_in[5];
  const float* b2 = (const float*)d_in[6];
  const float* W3 = (const float*)d_in[7];
  const float* b3 = (const float*)d_in[8];
  const float* g1 = (const float*)d_in[9];
  const float* be1 = (const float*)d_in[10];
  const float* m1 = (const float*)d_in[11];
  const float* v1 = (const float*)d_in[12];
  const float* g2 = (const float*)d_in[13];
  const float* be2 = (const float*)d_in[14];
  const float* m2 = (const float*)d_in[15];
  const float* v2 = (const float*)d_in[16];
  float* out = (float*)d_out;
  const int* src = ei;        // edge_index[0]
  const int* dstp = ei + EE;  // edge_index[1]

  float* ws = (float*)d_ws;
  float* dis = ws;
  float* nrm = ws + OFF_NRM;
  float* s1 = ws + OFF_AFF;
  float* u1 = s1 + 256;
  float* s2 = u1 + 256;
  float* u2 = s2 + 256;
  float* hW = ws + OFF_HW;
  float* h  = ws + OFF_H;
  float* ob = ws + OFF_OB;   // layer-3 accumulator (never touch d_out with atomics)

  dim3 b256(256);
  k_deg_init<<<(NN + 255) / 256, b256, 0, stream>>>(dis);
  k_deg_acc<<<(EE + 255) / 256, b256, 0, stream>>>(dstp, ew, dis);
  k_dis<<<(NN + 255) / 256, b256, 0, stream>>>(dis);
  k_affine<<<1, b256, 0, stream>>>(g1, be1, m1, v1, g2, be2, m2, v2, s1, u1, s2, u2);
  k_edgenorm<<<(EE + 255) / 256, b256, 0, stream>>>(src, dstp, ew, dis, nrm);

  dim3 g12(4, (NN + 63) / 64);
  dim3 g3(2, (NN + 63) / 64);
  // Layer 1
  k_gemm<<<g12, b256, 0, stream>>>(x, W1, hW, nullptr, nullptr, NN, 768, 256, 0);
  k_self256<<<(NN * 64 + 255) / 256, b256, 0, stream>>>(hW, dis, b1, h);
  k_scatter256<<<(EE + 3) / 4, b256, 0, stream>>>(hW, nrm, src, dstp, h);
  // Layer 2 (BN1+ReLU fused into A-load)
  k_gemm<<<g12, b256, 0, stream>>>(h, W2, hW, s1, u1, NN, 256, 256, 1);
  k_self256<<<(NN * 64 + 255) / 256, b256, 0, stream>>>(hW, dis, b2, h);
  k_scatter256<<<(EE + 3) / 4, b256, 0, stream>>>(hW, nrm, src, dstp, h);
  // Layer 3 (BN2+ReLU fused into A-load) -> accumulate in ws, not d_out
  k_gemm<<<g3, b256, 0, stream>>>(h, W3, hW, s2, u2, NN, 256, 128, 1);
  k_self128<<<(NN * 32 + 255) / 256, b256, 0, stream>>>(hW, dis, b3, ob);
  k_scatter128<<<(EE + 3) / 4, b256, 0, stream>>>(hW, nrm, src, dstp, ob);
  // Final: read ob, plain coalesced stores to d_out (write-only)
  k_l2<<<(NN + 3) / 4, b256, 0, stream>>>(ob, out);
}

// Round 5
// 1031.869 us; speedup vs baseline: 6.4712x; 6.4712x over previous
//
#include <hip/hip_runtime.h>
#include <cstddef>

#define NN 50000
#define EE 800000
#define NB 196  // ceil(50000/256)

// ============ CSR build ============
__global__ void k_zero_off(int* __restrict__ off) {
  int i = blockIdx.x * 256 + threadIdx.x;
  if (i <= NN) off[i] = 0;
}

__global__ void k_count(const int* __restrict__ src, const int* __restrict__ dst,
                        int* __restrict__ off) {
  int e = blockIdx.x * 256 + threadIdx.x;
  if (e < EE) {
    int s = src[e], d = dst[e];
    if (s >= 0 && s < NN && d >= 0 && d < NN) atomicAdd(&off[d], 1);
  }
}

// per-block exclusive scan; block sums out
__global__ void k_scanA(int* __restrict__ off, int* __restrict__ bsum) {
  __shared__ int sh[256];
  int t = threadIdx.x;
  int idx = blockIdx.x * 256 + t;
  int v = (idx < NN) ? off[idx] : 0;
  sh[t] = v;
  __syncthreads();
  for (int d = 1; d < 256; d <<= 1) {
    int x = (t >= d) ? sh[t - d] : 0;
    __syncthreads();
    sh[t] += x;
    __syncthreads();
  }
  if (idx < NN) off[idx] = sh[t] - v;  // exclusive within block
  if (t == 255) bsum[blockIdx.x] = sh[255];
}

// scan the block sums (single block); also writes off[NN] = total valid edges
__global__ void k_scanB(int* __restrict__ bsum, int* __restrict__ bpre,
                        int* __restrict__ off) {
  __shared__ int sh[256];
  int t = threadIdx.x;
  int v = (t < NB) ? bsum[t] : 0;
  sh[t] = v;
  __syncthreads();
  for (int d = 1; d < 256; d <<= 1) {
    int x = (t >= d) ? sh[t - d] : 0;
    __syncthreads();
    sh[t] += x;
    __syncthreads();
  }
  if (t < NB) bpre[t] = sh[t] - v;
  if (t == 255) off[NN] = sh[255];
}

__global__ void k_scanC(int* __restrict__ off, const int* __restrict__ bpre,
                        int* __restrict__ cursor) {
  int idx = blockIdx.x * 256 + threadIdx.x;
  if (idx < NN) {
    int o = off[idx] + bpre[blockIdx.x];
    off[idx] = o;
    cursor[idx] = o;
  }
}

__global__ void k_fill(const int* __restrict__ src, const int* __restrict__ dst,
                       const float* __restrict__ ew, int* __restrict__ cursor,
                       int* __restrict__ csrc, float* __restrict__ cew) {
  int e = blockIdx.x * 256 + threadIdx.x;
  if (e < EE) {
    int s = src[e], d = dst[e];
    if (s >= 0 && s < NN && d >= 0 && d < NN) {
      int p = atomicAdd(&cursor[d], 1);
      csrc[p] = s;
      cew[p] = ew[e];
    }
  }
}

// dis[i] = rsqrt(1 + sum of incoming ew)
__global__ void k_degdis(const int* __restrict__ off, const float* __restrict__ cew,
                         float* __restrict__ dis) {
  int i = blockIdx.x * 256 + threadIdx.x;
  if (i >= NN) return;
  int e0 = off[i], e1 = off[i + 1];
  float s = 1.0f;
  for (int e = e0; e < e1; ++e) s += cew[e];
  dis[i] = rsqrtf(s);
}

// BN folded to per-feature affine: bn(h) = h*s + (beta - mean*s)
__global__ void k_affine(const float* __restrict__ g1, const float* __restrict__ be1,
                         const float* __restrict__ m1, const float* __restrict__ v1,
                         const float* __restrict__ g2, const float* __restrict__ be2,
                         const float* __restrict__ m2, const float* __restrict__ v2,
                         float* __restrict__ s1, float* __restrict__ u1,
                         float* __restrict__ s2, float* __restrict__ u2) {
  int f = threadIdx.x;
  float a1 = g1[f] * rsqrtf(v1[f] + 1e-5f);
  s1[f] = a1; u1[f] = be1[f] - m1[f] * a1;
  float a2 = g2[f] * rsqrtf(v2[f] + 1e-5f);
  s2[f] = a2; u2[f] = be2[f] - m2[f] * a2;
}

// ============ fp32 tiled GEMM (known-good from R4) ============
__global__ __launch_bounds__(256) void k_gemm(const float* __restrict__ A,
                                              const float* __restrict__ B,
                                              float* __restrict__ C,
                                              const float* __restrict__ s,
                                              const float* __restrict__ u,
                                              int M, int K, int NOUT, int fuse) {
  __shared__ float As[16][68];
  __shared__ float Bs[16][68];
  const int tid = threadIdx.x;
  const int bm = blockIdx.y << 6;
  const int bn = blockIdx.x << 6;
  const int tx = tid & 15, ty = tid >> 4;
  const int arow = tid >> 2, acol = (tid & 3) << 2;
  const int brow = tid >> 4, bcol = (tid & 15) << 2;
  float acc[4][4] = {};
  const int gr = bm + arow;
  const float* Aptr = A + (size_t)gr * K;

  for (int k0 = 0; k0 < K; k0 += 16) {
    float4 av = make_float4(0.f, 0.f, 0.f, 0.f);
    if (gr < M) {
      av = *(const float4*)(Aptr + k0 + acol);
      if (fuse) {
        int kk = k0 + acol;
        av.x = fmaxf(fmaf(av.x, s[kk + 0], u[kk + 0]), 0.f);
        av.y = fmaxf(fmaf(av.y, s[kk + 1], u[kk + 1]), 0.f);
        av.z = fmaxf(fmaf(av.z, s[kk + 2], u[kk + 2]), 0.f);
        av.w = fmaxf(fmaf(av.w, s[kk + 3], u[kk + 3]), 0.f);
      }
    }
    float4 bv = *(const float4*)(B + (size_t)(k0 + brow) * NOUT + bn + bcol);
    As[acol + 0][arow] = av.x;
    As[acol + 1][arow] = av.y;
    As[acol + 2][arow] = av.z;
    As[acol + 3][arow] = av.w;
    *(float4*)&Bs[brow][bcol] = bv;
    __syncthreads();
#pragma unroll
    for (int k = 0; k < 16; ++k) {
      float4 rav = *(const float4*)&As[k][ty << 2];
      float4 rbv = *(const float4*)&Bs[k][tx << 2];
      float ar[4] = {rav.x, rav.y, rav.z, rav.w};
      float br[4] = {rbv.x, rbv.y, rbv.z, rbv.w};
#pragma unroll
      for (int r = 0; r < 4; ++r)
#pragma unroll
        for (int c = 0; c < 4; ++c) acc[r][c] = fmaf(ar[r], br[c], acc[r][c]);
    }
    __syncthreads();
  }
#pragma unroll
  for (int r = 0; r < 4; ++r) {
    int grow = bm + (ty << 2) + r;
    if (grow < M) {
      float4 v = make_float4(acc[r][0], acc[r][1], acc[r][2], acc[r][3]);
      *(float4*)(C + (size_t)grow * NOUT + bn + (tx << 2)) = v;
    }
  }
}

// ============ CSR aggregation: one wave per dst node ============
// out[i] = b + dis[i]^2 * hW[i] + sum_e dis[src_e]*cew_e*dis[i] * hW[src_e]
__global__ __launch_bounds__(256) void k_agg256(const float* __restrict__ hW,
                                                const float* __restrict__ dis,
                                                const float* __restrict__ b,
                                                const int* __restrict__ off,
                                                const int* __restrict__ csrc,
                                                const float* __restrict__ cew,
                                                float* __restrict__ out) {
  int i = (blockIdx.x << 2) + (threadIdx.x >> 6);
  if (i >= NN) return;
  int lane = threadIdx.x & 63;
  const float4* H = (const float4*)hW;  // row = 64 float4
  float di = dis[i];
  float4 bb = *(const float4*)(b + (lane << 2));
  float4 hv = H[(size_t)i * 64 + lane];
  float d2 = di * di;
  float4 acc;
  acc.x = fmaf(hv.x, d2, bb.x);
  acc.y = fmaf(hv.y, d2, bb.y);
  acc.z = fmaf(hv.z, d2, bb.z);
  acc.w = fmaf(hv.w, d2, bb.w);
  int e0 = off[i], e1 = off[i + 1];
  int e = e0;
  for (; e + 1 < e1; e += 2) {
    int s0 = csrc[e], s1 = csrc[e + 1];
    float w0 = dis[s0] * cew[e] * di;
    float w1 = dis[s1] * cew[e + 1] * di;
    float4 r0 = H[(size_t)s0 * 64 + lane];
    float4 r1 = H[(size_t)s1 * 64 + lane];
    acc.x = fmaf(r0.x, w0, acc.x); acc.y = fmaf(r0.y, w0, acc.y);
    acc.z = fmaf(r0.z, w0, acc.z); acc.w = fmaf(r0.w, w0, acc.w);
    acc.x = fmaf(r1.x, w1, acc.x); acc.y = fmaf(r1.y, w1, acc.y);
    acc.z = fmaf(r1.z, w1, acc.z); acc.w = fmaf(r1.w, w1, acc.w);
  }
  if (e < e1) {
    int s0 = csrc[e];
    float w0 = dis[s0] * cew[e] * di;
    float4 r0 = H[(size_t)s0 * 64 + lane];
    acc.x = fmaf(r0.x, w0, acc.x); acc.y = fmaf(r0.y, w0, acc.y);
    acc.z = fmaf(r0.z, w0, acc.z); acc.w = fmaf(r0.w, w0, acc.w);
  }
  *(float4*)(out + (size_t)i * 256 + (lane << 2)) = acc;
}

// layer-3 aggregation (F=128, float2/lane) + fused row L2 norm, write-only to d_out
__global__ __launch_bounds__(256) void k_agg128_l2(const float* __restrict__ hW,
                                                   const float* __restrict__ dis,
                                                   const float* __restrict__ b,
                                                   const int* __restrict__ off,
                                                   const int* __restrict__ csrc,
                                                   const float* __restrict__ cew,
                                                   float* __restrict__ out) {
  int i = (blockIdx.x << 2) + (threadIdx.x >> 6);
  if (i >= NN) return;
  int lane = threadIdx.x & 63;
  const float2* H = (const float2*)hW;  // row = 64 float2
  float di = dis[i];
  float2 bb = *(const float2*)(b + (lane << 1));
  float2 hv = H[(size_t)i * 64 + lane];
  float d2 = di * di;
  float2 acc;
  acc.x = fmaf(hv.x, d2, bb.x);
  acc.y = fmaf(hv.y, d2, bb.y);
  int e0 = off[i], e1 = off[i + 1];
  int e = e0;
  for (; e + 1 < e1; e += 2) {
    int s0 = csrc[e], s1 = csrc[e + 1];
    float w0 = dis[s0] * cew[e] * di;
    float w1 = dis[s1] * cew[e + 1] * di;
    float2 r0 = H[(size_t)s0 * 64 + lane];
    float2 r1 = H[(size_t)s1 * 64 + lane];
    acc.x = fmaf(r0.x, w0, acc.x); acc.y = fmaf(r0.y, w0, acc.y);
    acc.x = fmaf(r1.x, w1, acc.x); acc.y = fmaf(r1.y, w1, acc.y);
  }
  if (e < e1) {
    int s0 = csrc[e];
    float w0 = dis[s0] * cew[e] * di;
    float2 r0 = H[(size_t)s0 * 64 + lane];
    acc.x = fmaf(r0.x, w0, acc.x); acc.y = fmaf(r0.y, w0, acc.y);
  }
  float ss = fmaf(acc.x, acc.x, acc.y * acc.y);
#pragma unroll
  for (int o = 32; o > 0; o >>= 1) ss += __shfl_xor(ss, o, 64);
  float sc = 1.0f / fmaxf(sqrtf(ss), 1e-12f);
  acc.x *= sc;
  acc.y *= sc;
  *(float2*)(out + (size_t)i * 128 + (lane << 1)) = acc;
}

extern "C" void kernel_launch(void* const* d_in, const int* in_sizes, int n_in,
                              void* d_out, int out_size, void* d_ws, size_t ws_size,
                              hipStream_t stream) {
  // ws layout in 4-byte units:
  //   off   [0, 50176)            int  (N+1 used)
  //   cursor[50176, 100352)       int
  //   bsum  [100352, 100608)      int
  //   bpre  [100608, 100864)      int
  //   csrc  [100864, 900864)      int  (E)
  //   cew   [900864, 1700864)     float(E)
  //   dis   [1700864, 1751040)    float
  //   s1/u1/s2/u2 [1751040, 1752064)
  //   hW    [1752064, +N*256)     float
  //   h     [..., +N*256)         float
  const size_t OFF_CUR = 50176, OFF_BS = 100352, OFF_BP = 100608;
  const size_t OFF_CS = 100864, OFF_CW = 900864, OFF_DIS = 1700864;
  const size_t OFF_AFF = 1751040, OFF_HW = 1752064;
  const size_t OFF_H = OFF_HW + (size_t)NN * 256;
  const size_t WS_UNITS = OFF_H + (size_t)NN * 256 + 256;
  if (ws_size < WS_UNITS * 4) return;  // fail cleanly, never OOB

  const float* x  = (const float*)d_in[0];
  const int* ei   = (const int*)d_in[1];
  const float* ew = (const float*)d_in[2];
  const float* W1 = (const float*)d_in[3];
  const float* b1 = (const float*)d_in[4];
  const float* W2 = (const float*)d_in[5];
  const float* b2 = (const float*)d_in[6];
  const float* W3 = (const float*)d_in[7];
  const float* b3 = (const float*)d_in[8];
  const float* g1 = (const float*)d_in[9];
  const float* be1 = (const float*)d_in[10];
  const float* m1 = (const float*)d_in[11];
  const float* v1 = (const float*)d_in[12];
  const float* g2 = (const float*)d_in[13];
  const float* be2 = (const float*)d_in[14];
  const float* m2 = (const float*)d_in[15];
  const float* v2 = (const float*)d_in[16];
  float* out = (float*)d_out;
  const int* src = ei;
  const int* dstp = ei + EE;

  int* wsi = (int*)d_ws;
  float* wsf = (float*)d_ws;
  int* off = wsi;
  int* cursor = wsi + OFF_CUR;
  int* bsum = wsi + OFF_BS;
  int* bpre = wsi + OFF_BP;
  int* csrc = wsi + OFF_CS;
  float* cew = wsf + OFF_CW;
  float* dis = wsf + OFF_DIS;
  float* s1 = wsf + OFF_AFF;
  float* u1 = s1 + 256;
  float* s2 = u1 + 256;
  float* u2 = s2 + 256;
  float* hW = wsf + OFF_HW;
  float* h  = wsf + OFF_H;

  dim3 b256(256);
  const int EB = (EE + 255) / 256;
  // CSR build
  k_zero_off<<<NB, b256, 0, stream>>>(off);
  k_count<<<EB, b256, 0, stream>>>(src, dstp, off);
  k_scanA<<<NB, b256, 0, stream>>>(off, bsum);
  k_scanB<<<1, b256, 0, stream>>>(bsum, bpre, off);
  k_scanC<<<NB, b256, 0, stream>>>(off, bpre, cursor);
  k_fill<<<EB, b256, 0, stream>>>(src, dstp, ew, cursor, csrc, cew);
  k_degdis<<<NB, b256, 0, stream>>>(off, cew, dis);
  k_affine<<<1, b256, 0, stream>>>(g1, be1, m1, v1, g2, be2, m2, v2, s1, u1, s2, u2);

  dim3 g12(4, (NN + 63) / 64);
  dim3 g3(2, (NN + 63) / 64);
  const int AGB = (NN + 3) / 4;
  // Layer 1
  k_gemm<<<g12, b256, 0, stream>>>(x, W1, hW, nullptr, nullptr, NN, 768, 256, 0);
  k_agg256<<<AGB, b256, 0, stream>>>(hW, dis, b1, off, csrc, cew, h);
  // Layer 2 (BN1+ReLU fused into GEMM A-load)
  k_gemm<<<g12, b256, 0, stream>>>(h, W2, hW, s1, u1, NN, 256, 256, 1);
  k_agg256<<<AGB, b256, 0, stream>>>(hW, dis, b2, off, csrc, cew, h);
  // Layer 3 + fused L2 norm -> d_out (plain stores only)
  k_gemm<<<g3, b256, 0, stream>>>(h, W3, hW, s2, u2, NN, 256, 128, 1);
  k_agg128_l2<<<AGB, b256, 0, stream>>>(hW, dis, b3, off, csrc, cew, out);
}

// Round 6
// 743.975 us; speedup vs baseline: 8.9753x; 1.3870x over previous
//
#include <hip/hip_runtime.h>
#include <cstddef>

#define NN 50000
#define EE 800000
#define NB 196  // ceil(50000/256)

typedef __attribute__((ext_vector_type(8))) short short8v;
typedef __attribute__((ext_vector_type(4))) float f32x4;

__device__ __forceinline__ unsigned pk2bf(float a, float b) {
  unsigned ua = __float_as_uint(a), ub = __float_as_uint(b);
  ua = (ua + 0x7FFFu + ((ua >> 16) & 1u)) >> 16;
  ub = (ub + 0x7FFFu + ((ub >> 16) & 1u)) >> 16;
  return ua | (ub << 16);
}

__device__ __forceinline__ unsigned short f2bf(float a) {
  unsigned ua = __float_as_uint(a);
  return (unsigned short)((ua + 0x7FFFu + ((ua >> 16) & 1u)) >> 16);
}

// ============ CSR build ============
__global__ void k_zero_off(int* __restrict__ off) {
  int i = blockIdx.x * 256 + threadIdx.x;
  if (i <= NN) off[i] = 0;
}

__global__ void k_count(const int* __restrict__ src, const int* __restrict__ dst,
                        int* __restrict__ off) {
  int e = blockIdx.x * 256 + threadIdx.x;
  if (e < EE) {
    int s = src[e], d = dst[e];
    if (s >= 0 && s < NN && d >= 0 && d < NN) atomicAdd(&off[d], 1);
  }
}

__global__ void k_scanA(int* __restrict__ off, int* __restrict__ bsum) {
  __shared__ int sh[256];
  int t = threadIdx.x;
  int idx = blockIdx.x * 256 + t;
  int v = (idx < NN) ? off[idx] : 0;
  sh[t] = v;
  __syncthreads();
  for (int d = 1; d < 256; d <<= 1) {
    int x = (t >= d) ? sh[t - d] : 0;
    __syncthreads();
    sh[t] += x;
    __syncthreads();
  }
  if (idx < NN) off[idx] = sh[t] - v;
  if (t == 255) bsum[blockIdx.x] = sh[255];
}

__global__ void k_scanB(int* __restrict__ bsum, int* __restrict__ bpre,
                        int* __restrict__ off) {
  __shared__ int sh[256];
  int t = threadIdx.x;
  int v = (t < NB) ? bsum[t] : 0;
  sh[t] = v;
  __syncthreads();
  for (int d = 1; d < 256; d <<= 1) {
    int x = (t >= d) ? sh[t - d] : 0;
    __syncthreads();
    sh[t] += x;
    __syncthreads();
  }
  if (t < NB) bpre[t] = sh[t] - v;
  if (t == 255) off[NN] = sh[255];
}

__global__ void k_scanC(int* __restrict__ off, const int* __restrict__ bpre,
                        int* __restrict__ cursor) {
  int idx = blockIdx.x * 256 + threadIdx.x;
  if (idx < NN) {
    int o = off[idx] + bpre[blockIdx.x];
    off[idx] = o;
    cursor[idx] = o;
  }
}

__global__ void k_fill(const int* __restrict__ src, const int* __restrict__ dst,
                       const float* __restrict__ ew, int* __restrict__ cursor,
                       int* __restrict__ csrc, float* __restrict__ cew) {
  int e = blockIdx.x * 256 + threadIdx.x;
  if (e < EE) {
    int s = src[e], d = dst[e];
    if (s >= 0 && s < NN && d >= 0 && d < NN) {
      int p = atomicAdd(&cursor[d], 1);
      csrc[p] = s;
      cew[p] = ew[e];
    }
  }
}

__global__ void k_degdis(const int* __restrict__ off, const float* __restrict__ cew,
                         float* __restrict__ dis) {
  int i = blockIdx.x * 256 + threadIdx.x;
  if (i >= NN) return;
  int e0 = off[i], e1 = off[i + 1];
  float s = 1.0f;
  for (int e = e0; e < e1; ++e) s += cew[e];
  dis[i] = rsqrtf(s);
}

__global__ void k_affine(const float* __restrict__ g1, const float* __restrict__ be1,
                         const float* __restrict__ m1, const float* __restrict__ v1,
                         const float* __restrict__ g2, const float* __restrict__ be2,
                         const float* __restrict__ m2, const float* __restrict__ v2,
                         float* __restrict__ s1, float* __restrict__ u1,
                         float* __restrict__ s2, float* __restrict__ u2) {
  int f = threadIdx.x;
  float a1 = g1[f] * rsqrtf(v1[f] + 1e-5f);
  s1[f] = a1; u1[f] = be1[f] - m1[f] * a1;
  float a2 = g2[f] * rsqrtf(v2[f] + 1e-5f);
  s2[f] = a2; u2[f] = be2[f] - m2[f] * a2;
}

// ============ weight transpose+convert: WT[n][k] = bf16(W[k][n]) ============
__global__ void k_wt(const float* __restrict__ W, unsigned short* __restrict__ WT,
                     int K, int N) {
  int k = blockIdx.x * 256 + threadIdx.x;
  int n = blockIdx.y;
  if (k < K) WT[(size_t)n * K + k] = f2bf(W[(size_t)k * N + n]);
}

// ============ bf16 MFMA GEMM: C[M,Nout](fp32) = A[M,K] @ BT[Nout,K]^T ============
// 128x128 tile, BK=32, 4 waves, each wave 64x64 via 4x4 grid of 16x16x32 MFMA.
// a_fp32: A is fp32 (converted to bf16 during staging); else A is bf16.
#define LDA 40  // LDS row stride in shorts (32 + 8 pad): 80B rows, 2-way max aliasing
__global__ __launch_bounds__(256) void k_gemm_mfma(const void* __restrict__ Ain,
                                                   const unsigned short* __restrict__ BT,
                                                   float* __restrict__ C,
                                                   int M, int K, int Nout, int a_fp32) {
  __shared__ unsigned short As[128 * LDA];
  __shared__ unsigned short Bs[128 * LDA];
  const int tid = threadIdx.x;
  const int bm = blockIdx.y << 7;
  const int bn = blockIdx.x << 7;
  const int lane = tid & 63;
  const int wid = tid >> 6;
  const int wm = (wid & 1) << 6;   // wave row offset in tile
  const int wn = (wid >> 1) << 6;  // wave col offset
  const int quad = lane >> 4;
  const int l16 = lane & 15;

  f32x4 acc[4][4] = {};

  for (int k0 = 0; k0 < K; k0 += 32) {
    // ---- stage A, B tiles (each 128 rows x 32 bf16 = 512 x 16B chunks) ----
#pragma unroll
    for (int j = 0; j < 2; ++j) {
      int c = tid + (j << 8);
      int row = c >> 2, kc = c & 3;  // kc: which 8-element k-chunk
      // A
      uint4 va = make_uint4(0, 0, 0, 0);
      int gr = bm + row;
      if (gr < M) {
        if (a_fp32) {
          const float* p = (const float*)Ain + (size_t)gr * K + k0 + (kc << 3);
          float4 f0 = *(const float4*)p;
          float4 f1 = *(const float4*)(p + 4);
          va.x = pk2bf(f0.x, f0.y);
          va.y = pk2bf(f0.z, f0.w);
          va.z = pk2bf(f1.x, f1.y);
          va.w = pk2bf(f1.z, f1.w);
        } else {
          va = *(const uint4*)((const unsigned short*)Ain + (size_t)gr * K + k0 + (kc << 3));
        }
      }
      *(uint4*)&As[row * LDA + (kc << 3)] = va;
      // B (Nout multiple of 128 in all our calls -> no guard)
      uint4 vb = *(const uint4*)(BT + (size_t)(bn + row) * K + k0 + (kc << 3));
      *(uint4*)&Bs[row * LDA + (kc << 3)] = vb;
    }
    __syncthreads();
    // ---- compute: 4 A-frags, 4 B-frags, 16 MFMA ----
    short8v af[4], bfr[4];
#pragma unroll
    for (int mt = 0; mt < 4; ++mt)
      af[mt] = *(const short8v*)&As[(wm + (mt << 4) + l16) * LDA + (quad << 3)];
#pragma unroll
    for (int nt = 0; nt < 4; ++nt)
      bfr[nt] = *(const short8v*)&Bs[(wn + (nt << 4) + l16) * LDA + (quad << 3)];
#pragma unroll
    for (int mt = 0; mt < 4; ++mt)
#pragma unroll
      for (int nt = 0; nt < 4; ++nt)
        acc[mt][nt] = __builtin_amdgcn_mfma_f32_16x16x32_bf16(af[mt], bfr[nt], acc[mt][nt], 0, 0, 0);
    __syncthreads();
  }

  // ---- epilogue: C/D layout col=lane&15, row=quad*4+reg ----
  const int rbase = bm + wm + (quad << 2);
#pragma unroll
  for (int mt = 0; mt < 4; ++mt) {
#pragma unroll
    for (int reg = 0; reg < 4; ++reg) {
      int r = rbase + (mt << 4) + reg;
      if (r < M) {
        float* crow = C + (size_t)r * Nout + bn + wn + l16;
#pragma unroll
        for (int nt = 0; nt < 4; ++nt) crow[nt << 4] = acc[mt][nt][reg];
      }
    }
  }
}

// ============ CSR aggregation (F=256) + fused BN affine + ReLU -> bf16 out ============
__global__ __launch_bounds__(256) void k_agg256(const float* __restrict__ hW,
                                                const float* __restrict__ dis,
                                                const float* __restrict__ b,
                                                const int* __restrict__ off,
                                                const int* __restrict__ csrc,
                                                const float* __restrict__ cew,
                                                const float* __restrict__ s,
                                                const float* __restrict__ u,
                                                unsigned short* __restrict__ hout) {
  int i = (blockIdx.x << 2) + (threadIdx.x >> 6);
  if (i >= NN) return;
  int lane = threadIdx.x & 63;
  const float4* H = (const float4*)hW;  // row = 64 float4
  float di = dis[i];
  float4 bb = *(const float4*)(b + (lane << 2));
  float4 hv = H[(size_t)i * 64 + lane];
  float d2 = di * di;
  float4 acc;
  acc.x = fmaf(hv.x, d2, bb.x);
  acc.y = fmaf(hv.y, d2, bb.y);
  acc.z = fmaf(hv.z, d2, bb.z);
  acc.w = fmaf(hv.w, d2, bb.w);
  int e0 = off[i], e1 = off[i + 1];
  int e = e0;
  for (; e + 1 < e1; e += 2) {
    int s0 = csrc[e], s1i = csrc[e + 1];
    float w0 = dis[s0] * cew[e] * di;
    float w1 = dis[s1i] * cew[e + 1] * di;
    float4 r0 = H[(size_t)s0 * 64 + lane];
    float4 r1 = H[(size_t)s1i * 64 + lane];
    acc.x = fmaf(r0.x, w0, acc.x); acc.y = fmaf(r0.y, w0, acc.y);
    acc.z = fmaf(r0.z, w0, acc.z); acc.w = fmaf(r0.w, w0, acc.w);
    acc.x = fmaf(r1.x, w1, acc.x); acc.y = fmaf(r1.y, w1, acc.y);
    acc.z = fmaf(r1.z, w1, acc.z); acc.w = fmaf(r1.w, w1, acc.w);
  }
  if (e < e1) {
    int s0 = csrc[e];
    float w0 = dis[s0] * cew[e] * di;
    float4 r0 = H[(size_t)s0 * 64 + lane];
    acc.x = fmaf(r0.x, w0, acc.x); acc.y = fmaf(r0.y, w0, acc.y);
    acc.z = fmaf(r0.z, w0, acc.z); acc.w = fmaf(r0.w, w0, acc.w);
  }
  // BN affine + ReLU + bf16 pack
  float4 sv = *(const float4*)(s + (lane << 2));
  float4 uv = *(const float4*)(u + (lane << 2));
  float r0 = fmaxf(fmaf(acc.x, sv.x, uv.x), 0.f);
  float r1 = fmaxf(fmaf(acc.y, sv.y, uv.y), 0.f);
  float r2 = fmaxf(fmaf(acc.z, sv.z, uv.z), 0.f);
  float r3 = fmaxf(fmaf(acc.w, sv.w, uv.w), 0.f);
  uint2 pk;
  pk.x = pk2bf(r0, r1);
  pk.y = pk2bf(r2, r3);
  *(uint2*)&hout[(size_t)i * 256 + (lane << 2)] = pk;
}

// ============ layer-3 aggregation (F=128) + fused L2 norm -> d_out (fp32) ============
__global__ __launch_bounds__(256) void k_agg128_l2(const float* __restrict__ hW,
                                                   const float* __restrict__ dis,
                                                   const float* __restrict__ b,
                                                   const int* __restrict__ off,
                                                   const int* __restrict__ csrc,
                                                   const float* __restrict__ cew,
                                                   float* __restrict__ out) {
  int i = (blockIdx.x << 2) + (threadIdx.x >> 6);
  if (i >= NN) return;
  int lane = threadIdx.x & 63;
  const float2* H = (const float2*)hW;  // row = 64 float2
  float di = dis[i];
  float2 bb = *(const float2*)(b + (lane << 1));
  float2 hv = H[(size_t)i * 64 + lane];
  float d2 = di * di;
  float2 acc;
  acc.x = fmaf(hv.x, d2, bb.x);
  acc.y = fmaf(hv.y, d2, bb.y);
  int e0 = off[i], e1 = off[i + 1];
  int e = e0;
  for (; e + 1 < e1; e += 2) {
    int s0 = csrc[e], s1i = csrc[e + 1];
    float w0 = dis[s0] * cew[e] * di;
    float w1 = dis[s1i] * cew[e + 1] * di;
    float2 r0 = H[(size_t)s0 * 64 + lane];
    float2 r1 = H[(size_t)s1i * 64 + lane];
    acc.x = fmaf(r0.x, w0, acc.x); acc.y = fmaf(r0.y, w0, acc.y);
    acc.x = fmaf(r1.x, w1, acc.x); acc.y = fmaf(r1.y, w1, acc.y);
  }
  if (e < e1) {
    int s0 = csrc[e];
    float w0 = dis[s0] * cew[e] * di;
    float2 r0 = H[(size_t)s0 * 64 + lane];
    acc.x = fmaf(r0.x, w0, acc.x); acc.y = fmaf(r0.y, w0, acc.y);
  }
  float ss = fmaf(acc.x, acc.x, acc.y * acc.y);
#pragma unroll
  for (int o = 32; o > 0; o >>= 1) ss += __shfl_xor(ss, o, 64);
  float sc = 1.0f / fmaxf(sqrtf(ss), 1e-12f);
  acc.x *= sc;
  acc.y *= sc;
  *(float2*)(out + (size_t)i * 128 + (lane << 1)) = acc;
}

extern "C" void kernel_launch(void* const* d_in, const int* in_sizes, int n_in,
                              void* d_out, int out_size, void* d_ws, size_t ws_size,
                              hipStream_t stream) {
  // ws layout (4-byte units):
  const size_t OFF_CUR = 50176, OFF_BS = 100352, OFF_BP = 100608;
  const size_t OFF_CS = 100864, OFF_CW = 900864, OFF_DIS = 1700864;
  const size_t OFF_AFF = 1751040, OFF_HW = 1752064;
  const size_t OFF_HB = OFF_HW + (size_t)NN * 256;        // bf16 h: NN*256 shorts
  const size_t OFF_WT1 = OFF_HB + (size_t)NN * 128;       // after 6.4M units
  const size_t OFF_WT2 = OFF_WT1 + 768 * 256 / 2;
  const size_t OFF_WT3 = OFF_WT2 + 256 * 256 / 2;
  const size_t WS_UNITS = OFF_WT3 + 256 * 128 / 2 + 256;
  if (ws_size < WS_UNITS * 4) return;  // fail cleanly, never OOB

  const float* x  = (const float*)d_in[0];
  const int* ei   = (const int*)d_in[1];
  const float* ew = (const float*)d_in[2];
  const float* W1 = (const float*)d_in[3];
  const float* b1 = (const float*)d_in[4];
  const float* W2 = (const float*)d_in[5];
  const float* b2 = (const float*)d_in[6];
  const float* W3 = (const float*)d_in[7];
  const float* b3 = (const float*)d_in[8];
  const float* g1 = (const float*)d_in[9];
  const float* be1 = (const float*)d_in[10];
  const float* m1 = (const float*)d_in[11];
  const float* v1 = (const float*)d_in[12];
  const float* g2 = (const float*)d_in[13];
  const float* be2 = (const float*)d_in[14];
  const float* m2 = (const float*)d_in[15];
  const float* v2 = (const float*)d_in[16];
  float* out = (float*)d_out;
  const int* src = ei;
  const int* dstp = ei + EE;

  int* wsi = (int*)d_ws;
  float* wsf = (float*)d_ws;
  int* off = wsi;
  int* cursor = wsi + OFF_CUR;
  int* bsum = wsi + OFF_BS;
  int* bpre = wsi + OFF_BP;
  int* csrc = wsi + OFF_CS;
  float* cew = wsf + OFF_CW;
  float* dis = wsf + OFF_DIS;
  float* s1 = wsf + OFF_AFF;
  float* u1 = s1 + 256;
  float* s2 = u1 + 256;
  float* u2 = s2 + 256;
  float* hW = wsf + OFF_HW;
  unsigned short* hb = (unsigned short*)(wsi + OFF_HB);
  unsigned short* wT1 = (unsigned short*)(wsi + OFF_WT1);
  unsigned short* wT2 = (unsigned short*)(wsi + OFF_WT2);
  unsigned short* wT3 = (unsigned short*)(wsi + OFF_WT3);

  dim3 b256(256);
  const int EB = (EE + 255) / 256;
  // CSR build + norm precompute
  k_zero_off<<<NB, b256, 0, stream>>>(off);
  k_count<<<EB, b256, 0, stream>>>(src, dstp, off);
  k_scanA<<<NB, b256, 0, stream>>>(off, bsum);
  k_scanB<<<1, b256, 0, stream>>>(bsum, bpre, off);
  k_scanC<<<NB, b256, 0, stream>>>(off, bpre, cursor);
  k_fill<<<EB, b256, 0, stream>>>(src, dstp, ew, cursor, csrc, cew);
  k_degdis<<<NB, b256, 0, stream>>>(off, cew, dis);
  k_affine<<<1, b256, 0, stream>>>(g1, be1, m1, v1, g2, be2, m2, v2, s1, u1, s2, u2);
  // weight transpose+convert
  k_wt<<<dim3(3, 256), b256, 0, stream>>>(W1, wT1, 768, 256);
  k_wt<<<dim3(1, 256), b256, 0, stream>>>(W2, wT2, 256, 256);
  k_wt<<<dim3(1, 128), b256, 0, stream>>>(W3, wT3, 256, 128);

  const int GM = (NN + 127) / 128;  // 391
  const int AGB = (NN + 3) / 4;
  // Layer 1: x (fp32, inline-converted) @ W1
  k_gemm_mfma<<<dim3(2, GM), b256, 0, stream>>>(x, wT1, hW, NN, 768, 256, 1);
  k_agg256<<<AGB, b256, 0, stream>>>(hW, dis, b1, off, csrc, cew, s1, u1, hb);
  // Layer 2: hb (bf16) @ W2
  k_gemm_mfma<<<dim3(2, GM), b256, 0, stream>>>(hb, wT2, hW, NN, 256, 256, 0);
  k_agg256<<<AGB, b256, 0, stream>>>(hW, dis, b2, off, csrc, cew, s2, u2, hb);
  // Layer 3: hb @ W3, then aggregate + L2 norm -> d_out
  k_gemm_mfma<<<dim3(1, GM), b256, 0, stream>>>(hb, wT3, hW, NN, 256, 128, 0);
  k_agg128_l2<<<AGB, b256, 0, stream>>>(hW, dis, b3, off, csrc, cew, out);
}